// Round 7
// baseline (39.279 us; speedup 1.0000x reference)
//
#include <hip/hip_runtime.h>
#include <math.h>

#define NPTS 4096
#define NB 16
#define THREADS 256
#define RADIUSF 0.07f
#define HF 0.03f
#define EPSF 1e-12f

#define GRIDD 16
#define NCELL (GRIDD * GRIDD * GRIDD)   // 4096
#define HCELL 0.0625f                   // cell edge
#define SW 5                            // search window (cells per axis)

// Insert d into sorted-ascending 6-list: L0'=min(L0,d), Lk'=med3(d,L(k-1),Lk).
#define INS6(L, dd) do {                                          \
    const float _d  = (dd);                                       \
    const float _n0 = fminf((L)[0], _d);                          \
    const float _n1 = __builtin_amdgcn_fmed3f(_d, (L)[0], (L)[1]);\
    const float _n2 = __builtin_amdgcn_fmed3f(_d, (L)[1], (L)[2]);\
    const float _n3 = __builtin_amdgcn_fmed3f(_d, (L)[2], (L)[3]);\
    const float _n4 = __builtin_amdgcn_fmed3f(_d, (L)[3], (L)[4]);\
    const float _n5 = __builtin_amdgcn_fmed3f(_d, (L)[4], (L)[5]);\
    (L)[0]=_n0; (L)[1]=_n1; (L)[2]=_n2; (L)[3]=_n3; (L)[4]=_n4; (L)[5]=_n5; \
} while (0)

__device__ __forceinline__ float loss5(const float* L) {
    float loss = 0.0f;
    #pragma unroll
    for (int i = 1; i < 6; ++i) {               // L[0] == self (exact 0)
        const float d = sqrtf(fmaxf(L[i], EPSF));
        const float t = d / HF;
        loss += (RADIUSF - d) * expf(-t * t);
    }
    return loss;
}

// ---------------------------------------------------------------------------
// Kernel A: per batch, bin points into 16^3 cells (counting sort).
// 1024 threads, 4 points & 4 cells per thread, vectorized float4 loads.
// ---------------------------------------------------------------------------
__global__ __launch_bounds__(1024) void bin_kernel(
    const float* __restrict__ pred, float4* __restrict__ sortedP,
    int* __restrict__ cellStart)
{
    __shared__ int h[NCELL];       // 16 KB
    __shared__ int cur[NCELL];     // 16 KB
    __shared__ int start[NCELL];   // 16 KB
    __shared__ int wsum[16], wpre[16];

    const int b = blockIdx.x, t = threadIdx.x;
    const int lane = t & 63, w = t >> 6;
    #pragma unroll
    for (int j = 0; j < 4; ++j) { h[4 * t + j] = 0; cur[4 * t + j] = 0; }
    __syncthreads();

    // 4 points per thread via 3 coalesced float4 loads.
    const float4* pb4 = (const float4*)(pred + (size_t)b * NPTS * 3);
    const float4 A = pb4[3 * t], B = pb4[3 * t + 1], C = pb4[3 * t + 2];
    const float px[4] = { A.x, A.w, B.z, C.y };
    const float py[4] = { A.y, B.x, B.w, C.z };
    const float pz[4] = { A.z, B.y, C.x, C.w };

    int cid[4];
    #pragma unroll
    for (int k = 0; k < 4; ++k) {
        const int ix = min(GRIDD - 1, max(0, (int)(px[k] * (float)GRIDD)));
        const int iy = min(GRIDD - 1, max(0, (int)(py[k] * (float)GRIDD)));
        const int iz = min(GRIDD - 1, max(0, (int)(pz[k] * (float)GRIDD)));
        cid[k] = (ix << 8) | (iy << 4) | iz;
        atomicAdd(&h[cid[k]], 1);
    }
    __syncthreads();

    // Scan: 4 cells/thread serial + 64-lane shfl scan + 16-wave prefix.
    const int h0 = h[4 * t], h1 = h[4 * t + 1], h2 = h[4 * t + 2], h3 = h[4 * t + 3];
    const int s = h0 + h1 + h2 + h3;
    int v = s;
    #pragma unroll
    for (int off = 1; off < 64; off <<= 1) {
        const int u = __shfl_up(v, off, 64);
        if (lane >= off) v += u;
    }
    if (lane == 63) wsum[w] = v;
    __syncthreads();
    if (t < 16) {
        int acc = 0;
        for (int i = 0; i < t; ++i) acc += wsum[i];
        wpre[t] = acc;
    }
    __syncthreads();
    const int base = wpre[w] + v - s;           // exclusive start of cell 4t
    start[4 * t + 0] = base;
    start[4 * t + 1] = base + h0;
    start[4 * t + 2] = base + h0 + h1;
    start[4 * t + 3] = base + h0 + h1 + h2;
    __syncthreads();

    #pragma unroll
    for (int k = 0; k < 4; ++k) {
        const int dst = start[cid[k]] + atomicAdd(&cur[cid[k]], 1);
        sortedP[(size_t)b * NPTS + dst] = make_float4(px[k], py[k], pz[k], 0.0f);
    }

    int* cso = cellStart + b * (NCELL + 1);
    #pragma unroll
    for (int k = 0; k < 4; ++k) cso[4 * t + k] = start[4 * t + k];
    if (t == 0) cso[NCELL] = NPTS;
}

// ---------------------------------------------------------------------------
// Kernel B: grid kNN search. Whole batch staged in LDS (64 KB points +
// 8 KB u16 cell table) -> candidate reads hit the LDS pipe, not the TA
// gather pipe. 2 lanes per query walk a flattened stream of the 25 z-row
// ranges of the shifted-clamped 5^3 window; 1 shfl_xor exact merge.
// Coverage proof (per-query radius >= 2h = 0.125) -> exact; rare failures
// brute-forced exactly from LDS, wave-cooperatively.
// ---------------------------------------------------------------------------
__global__ __launch_bounds__(THREADS, 2) void search_kernel(
    const float4* __restrict__ sortedP, const int* __restrict__ cellStart,
    float* __restrict__ partial)
{
    __shared__ __align__(16) float4 pts[NPTS];        // 64 KB
    __shared__ unsigned short cs[NCELL + 2];          // 8 KB (counts <= 4096)
    __shared__ float red[THREADS / 64];

    const int b     = blockIdx.x >> 5;                // batch
    const int chunk = blockIdx.x & 31;                // 128-query chunk
    const int t = threadIdx.x, lane = t & 63;

    const float4* sp = sortedP + (size_t)b * NPTS;
    #pragma unroll
    for (int i = 0; i < NPTS / THREADS; ++i)
        pts[i * THREADS + t] = sp[i * THREADS + t];
    const int* cbase = cellStart + b * (NCELL + 1);
    #pragma unroll
    for (int i = 0; i < (NCELL + THREADS) / THREADS; ++i) {
        const int idx = i * THREADS + t;
        if (idx < NCELL + 1) cs[idx] = (unsigned short)cbase[idx];
    }
    __syncthreads();

    const int qn = chunk * 128 + (t >> 1);            // query (sorted index)
    const int r  = t & 1;                             // sublane 0/1
    const float4 me = pts[qn];
    const int ix = min(GRIDD - 1, max(0, (int)(me.x * (float)GRIDD)));
    const int iy = min(GRIDD - 1, max(0, (int)(me.y * (float)GRIDD)));
    const int iz = min(GRIDD - 1, max(0, (int)(me.z * (float)GRIDD)));
    const int X0 = min(max(ix - 2, 0), GRIDD - SW);   // shifted-clamped window
    const int Y0 = min(max(iy - 2, 0), GRIDD - SW);
    const int Z0 = min(max(iz - 2, 0), GRIDD - SW);

    float L[6];
    #pragma unroll
    for (int i = 0; i < 6; ++i) L[i] = 1e30f;

    // Flattened walk of rows ridx = r, r+2, ..., 23/24 (i5 = ridx/5, j5 = ridx%5).
    // One candidate OR one row-advance per iteration -> no nested lockstep blowup.
    int i5 = 0, j5 = r;
    int p = 0, pe = 0;
    while (true) {
        while (p >= pe) {                             // fetch next nonempty row
            if (i5 >= SW) break;
            const int rb = ((X0 + i5) << 8) | ((Y0 + j5) << 4);
            p  = cs[rb + Z0];
            pe = cs[rb + Z0 + SW];
            j5 += 2;
            if (j5 >= SW) { j5 -= SW; ++i5; }
        }
        if (p >= pe) break;                           // stream exhausted
        const float4 c = pts[p++];
        const float ddx = c.x - me.x;
        const float ddy = c.y - me.y;
        const float ddz = c.z - me.z;
        const float d = fmaf(ddz, ddz, fmaf(ddy, ddy, ddx * ddx));
        INS6(L, d);
    }

    // Exact union-top-6 across the 2 disjoint sublane streams.
    {
        float R[6];
        #pragma unroll
        for (int i = 0; i < 6; ++i) R[i] = __shfl_xor(L[i], 1, 64);
        #pragma unroll
        for (int i = 0; i < 6; ++i) INS6(L, R[i]);
    }

    // Per-query coverage radius: distance to nearest non-boundary window face.
    float cov = 1e30f;
    if (X0 != 0)          cov = fminf(cov, me.x - (float)X0 * HCELL);
    if (X0 != GRIDD - SW) cov = fminf(cov, (float)(X0 + SW) * HCELL - me.x);
    if (Y0 != 0)          cov = fminf(cov, me.y - (float)Y0 * HCELL);
    if (Y0 != GRIDD - SW) cov = fminf(cov, (float)(Y0 + SW) * HCELL - me.y);
    if (Z0 != 0)          cov = fminf(cov, me.z - (float)Z0 * HCELL);
    if (Z0 != GRIDD - SW) cov = fminf(cov, (float)(Z0 + SW) * HCELL - me.z);

    const bool owner = (r == 0);
    const bool ok    = (L[5] <= cov * cov);
    float loss = (owner && ok) ? loss5(L) : 0.0f;

    // Exact full-batch scan from LDS for flagged queries (rare).
    unsigned long long flagged = __ballot(owner && !ok);
    while (flagged) {
        const int src = __ffsll(flagged) - 1;
        flagged &= flagged - 1;
        const float mx = __shfl(me.x, src, 64);
        const float my = __shfl(me.y, src, 64);
        const float mz = __shfl(me.z, src, 64);
        float F[6];
        #pragma unroll
        for (int i = 0; i < 6; ++i) F[i] = 1e30f;
        for (int p2 = lane; p2 < NPTS; p2 += 64) {
            const float4 c = pts[p2];
            const float ddx = c.x - mx;
            const float ddy = c.y - my;
            const float ddz = c.z - mz;
            const float d = fmaf(ddz, ddz, fmaf(ddy, ddy, ddx * ddx));
            INS6(F, d);
        }
        #pragma unroll
        for (int off = 32; off >= 1; off >>= 1) {     // tree merge -> lane 0
            float R[6];
            #pragma unroll
            for (int i = 0; i < 6; ++i) R[i] = __shfl_down(F[i], off, 64);
            #pragma unroll
            for (int i = 0; i < 6; ++i) INS6(F, R[i]);
        }
        if (lane == 0) loss += loss5(F);
    }

    #pragma unroll
    for (int off = 32; off > 0; off >>= 1)
        loss += __shfl_down(loss, off, 64);
    const int wave = t >> 6;
    if (lane == 0) red[wave] = loss;
    __syncthreads();
    if (t == 0) {
        float ssum = 0.0f;
        #pragma unroll
        for (int w = 0; w < THREADS / 64; ++w) ssum += red[w];
        partial[blockIdx.x] = ssum;   // block = 128 consecutive queries
    }
}

// 512 partials (32 per batch): thread t -> batch t>>4, 2 partials, 16-lane reduce.
__global__ void final_kernel(const float* __restrict__ partial,
                             float* __restrict__ out)
{
    const int t = threadIdx.x;
    const int bb = t >> 4, j = t & 15;
    float s = partial[bb * 32 + j] + partial[bb * 32 + 16 + j];
    #pragma unroll
    for (int off = 8; off > 0; off >>= 1)
        s += __shfl_down(s, off, 16);
    if (j == 0) out[bb] = s * (1.0f / ((float)NPTS * 5.0f));
}

// ---------------------------------------------------------------------------
// Emergency path (tiny workspace): monolithic brute force.
// ---------------------------------------------------------------------------
__global__ __launch_bounds__(THREADS) void mono_kernel(
    const float* __restrict__ pred, float* __restrict__ partial)
{
    __shared__ __align__(16) float sx[NPTS];
    __shared__ __align__(16) float sy[NPTS];
    __shared__ __align__(16) float sz[NPTS];
    __shared__ float red[THREADS / 64];

    const int b     = blockIdx.x >> 4;
    const int chunk = blockIdx.x & 15;
    const float* pb = pred + (size_t)b * NPTS * 3;

    for (int p = threadIdx.x; p < NPTS; p += THREADS) {
        sx[p] = pb[3 * p + 0]; sy[p] = pb[3 * p + 1]; sz[p] = pb[3 * p + 2];
    }
    __syncthreads();

    const int n = chunk * THREADS + threadIdx.x;
    const float qx = pb[3 * n], qy = pb[3 * n + 1], qz = pb[3 * n + 2];

    float A[6], B[6];
    #pragma unroll
    for (int i = 0; i < 6; ++i) { A[i] = 1e30f; B[i] = 1e30f; }

    const float4* X4 = (const float4*)sx;
    const float4* Y4 = (const float4*)sy;
    const float4* Z4 = (const float4*)sz;

    #pragma unroll 2
    for (int g = 0; g < NPTS / 4; ++g) {
        const float4 X = X4[g], Y = Y4[g], Z = Z4[g];
        const float dx0 = X.x - qx, dy0 = Y.x - qy, dz0 = Z.x - qz;
        const float dx1 = X.y - qx, dy1 = Y.y - qy, dz1 = Z.y - qz;
        const float dx2 = X.z - qx, dy2 = Y.z - qy, dz2 = Z.z - qz;
        const float dx3 = X.w - qx, dy3 = Y.w - qy, dz3 = Z.w - qz;
        const float d0 = fmaf(dz0, dz0, fmaf(dy0, dy0, dx0 * dx0));
        const float d1 = fmaf(dz1, dz1, fmaf(dy1, dy1, dx1 * dx1));
        const float d2 = fmaf(dz2, dz2, fmaf(dy2, dy2, dx2 * dx2));
        const float d3 = fmaf(dz3, dz3, fmaf(dy3, dy3, dx3 * dx3));
        INS6(A, d0);
        INS6(B, d1);
        INS6(A, d2);
        INS6(B, d3);
    }
    #pragma unroll
    for (int i = 0; i < 6; ++i) INS6(A, B[i]);

    float loss = loss5(A);
    #pragma unroll
    for (int off = 32; off > 0; off >>= 1)
        loss += __shfl_down(loss, off, 64);
    const int wave = threadIdx.x >> 6, lane = threadIdx.x & 63;
    if (lane == 0) red[wave] = loss;
    __syncthreads();
    if (threadIdx.x == 0) {
        float s = 0.0f;
        #pragma unroll
        for (int w = 0; w < THREADS / 64; ++w) s += red[w];
        partial[blockIdx.x] = s;
    }
}

__global__ void mono_final_kernel(const float* __restrict__ partial,
                                  float* __restrict__ out)
{
    const int b = threadIdx.x;
    if (b < NB) {
        float s = 0.0f;
        #pragma unroll
        for (int i = 0; i < 16; ++i) s += partial[b * 16 + i];
        out[b] = s * (1.0f / ((float)NPTS * 5.0f));
    }
}

extern "C" void kernel_launch(void* const* d_in, const int* in_sizes, int n_in,
                              void* d_out, int out_size, void* d_ws, size_t ws_size,
                              hipStream_t stream)
{
    const float* pred = (const float*)d_in[0];
    float* out        = (float*)d_out;
    char* ws          = (char*)d_ws;

    const size_t off_sorted = 0;                               // 1 MB
    const size_t off_cs     = off_sorted + (size_t)NB * NPTS * sizeof(float4);
    const size_t off_part   = off_cs + (size_t)NB * (NCELL + 1) * sizeof(int);
    const size_t need       = off_part + 512 * sizeof(float);

    if (ws_size >= need) {
        float4* sortedP = (float4*)(ws + off_sorted);
        int*    cellS   = (int*)(ws + off_cs);
        float*  partial = (float*)(ws + off_part);

        bin_kernel<<<dim3(NB), dim3(1024), 0, stream>>>(pred, sortedP, cellS);
        search_kernel<<<dim3(NB * 32), dim3(THREADS), 0, stream>>>(
            sortedP, cellS, partial);
        final_kernel<<<dim3(1), dim3(256), 0, stream>>>(partial, out);
    } else {
        float* partial = (float*)d_ws;                 // 256 floats
        mono_kernel<<<dim3(256), dim3(THREADS), 0, stream>>>(pred, partial);
        mono_final_kernel<<<dim3(1), dim3(64), 0, stream>>>(partial, out);
    }
}

// Round 8
// 34.133 us; speedup vs baseline: 1.1508x; 1.1508x over previous
//
#include <hip/hip_runtime.h>
#include <math.h>

#define NPTS 4096
#define NB 16
#define RADIUSF 0.07f
#define HF 0.03f
#define EPSF 1e-12f

#define GRIDD 8
#define NCELL (GRIDD * GRIDD * GRIDD)   // 512
#define HCELL 0.125f                    // cell edge
#define SW 3                            // search window (cells per axis)

// Insert d into sorted-ascending 6-list: L0'=min(L0,d), Lk'=med3(d,L(k-1),Lk).
#define INS6(L, dd) do {                                          \
    const float _d  = (dd);                                       \
    const float _n0 = fminf((L)[0], _d);                          \
    const float _n1 = __builtin_amdgcn_fmed3f(_d, (L)[0], (L)[1]);\
    const float _n2 = __builtin_amdgcn_fmed3f(_d, (L)[1], (L)[2]);\
    const float _n3 = __builtin_amdgcn_fmed3f(_d, (L)[2], (L)[3]);\
    const float _n4 = __builtin_amdgcn_fmed3f(_d, (L)[3], (L)[4]);\
    const float _n5 = __builtin_amdgcn_fmed3f(_d, (L)[4], (L)[5]);\
    (L)[0]=_n0; (L)[1]=_n1; (L)[2]=_n2; (L)[3]=_n3; (L)[4]=_n4; (L)[5]=_n5; \
} while (0)

__device__ __forceinline__ float loss5(const float* L) {
    float loss = 0.0f;
    #pragma unroll
    for (int i = 1; i < 6; ++i) {               // L[0] == self (exact 0)
        const float d = sqrtf(fmaxf(L[i], EPSF));
        const float t = d / HF;
        loss += (RADIUSF - d) * expf(-t * t);
    }
    return loss;
}

// ---------------------------------------------------------------------------
// Kernel A: per batch, bin points into 8^3 cells (counting sort).
// ---------------------------------------------------------------------------
__global__ __launch_bounds__(512) void bin_kernel(
    const float* __restrict__ pred, float4* __restrict__ sortedP,
    int* __restrict__ cellStart)
{
    __shared__ int h[NCELL];
    __shared__ int cur[NCELL];
    __shared__ int start[NCELL];
    __shared__ int wsum[8], wpre[8];

    const int b = blockIdx.x, t = threadIdx.x;
    const int lane = t & 63, w = t >> 6;
    h[t] = 0; cur[t] = 0;
    __syncthreads();

    const float* pb = pred + (size_t)b * NPTS * 3;
    int cid[8];
    #pragma unroll
    for (int k = 0; k < 8; ++k) {
        const int p = k * 512 + t;
        const float x = pb[3 * p], y = pb[3 * p + 1], z = pb[3 * p + 2];
        const int ix = min(GRIDD - 1, max(0, (int)(x * (float)GRIDD)));
        const int iy = min(GRIDD - 1, max(0, (int)(y * (float)GRIDD)));
        const int iz = min(GRIDD - 1, max(0, (int)(z * (float)GRIDD)));
        cid[k] = (ix << 6) | (iy << 3) | iz;
        atomicAdd(&h[cid[k]], 1);
    }
    __syncthreads();

    int v = h[t];
    #pragma unroll
    for (int off = 1; off < 64; off <<= 1) {
        const int u = __shfl_up(v, off, 64);
        if (lane >= off) v += u;
    }
    if (lane == 63) wsum[w] = v;
    __syncthreads();
    if (t < 8) {
        int s = 0;
        for (int i = 0; i < t; ++i) s += wsum[i];
        wpre[t] = s;
    }
    __syncthreads();
    start[t] = v + wpre[w] - h[t];               // exclusive start
    __syncthreads();

    #pragma unroll
    for (int k = 0; k < 8; ++k) {
        const int p = k * 512 + t;
        const float x = pb[3 * p], y = pb[3 * p + 1], z = pb[3 * p + 2];
        const int dst = start[cid[k]] + atomicAdd(&cur[cid[k]], 1);
        sortedP[(size_t)b * NPTS + dst] = make_float4(x, y, z, 0.0f);
    }

    cellStart[b * (NCELL + 1) + t] = start[t];
    if (t == 0) cellStart[b * (NCELL + 1) + NCELL] = NPTS;
}

// ---------------------------------------------------------------------------
// Kernel B: grid kNN search. 1024-thread blocks (16 waves), 2 blocks/CU,
// 8 waves/SIMD. Whole batch in LDS (64 KB pts + 1 KB u16 cell table).
// 8 sublanes per query, stride-8 within each of the 9 z-rows of the
// shifted-clamped 3^3 window; butterfly exact merge. Per-query coverage
// proof; rare failures brute-forced exactly from LDS.
// ---------------------------------------------------------------------------
__global__ __launch_bounds__(1024, 8) void search_kernel(
    const float4* __restrict__ sortedP, const int* __restrict__ cellStart,
    float* __restrict__ partial)
{
    __shared__ __align__(16) float4 pts[NPTS];        // 64 KB
    __shared__ unsigned short cs[NCELL + 1];          // 1 KB
    __shared__ float red[16];

    const int b     = blockIdx.x >> 5;                // batch
    const int chunk = blockIdx.x & 31;                // 128-query chunk
    const int t = threadIdx.x, lane = t & 63;

    const float4* sp = sortedP + (size_t)b * NPTS;
    #pragma unroll
    for (int i = 0; i < NPTS / 1024; ++i)
        pts[i * 1024 + t] = sp[i * 1024 + t];
    const int* cbase = cellStart + b * (NCELL + 1);
    if (t < NCELL + 1) cs[t] = (unsigned short)cbase[t];
    __syncthreads();

    const int qn = chunk * 128 + (t >> 3);            // query (sorted index)
    const int r  = t & 7;                             // sublane 0..7
    const float4 me = pts[qn];
    const int ix = min(GRIDD - 1, max(0, (int)(me.x * (float)GRIDD)));
    const int iy = min(GRIDD - 1, max(0, (int)(me.y * (float)GRIDD)));
    const int iz = min(GRIDD - 1, max(0, (int)(me.z * (float)GRIDD)));
    const int X0 = min(max(ix - 1, 0), GRIDD - SW);   // shifted-clamped window
    const int Y0 = min(max(iy - 1, 0), GRIDD - SW);
    const int Z0 = min(max(iz - 1, 0), GRIDD - SW);

    float L[6];
    #pragma unroll
    for (int i = 0; i < 6; ++i) L[i] = 1e30f;

    #pragma unroll
    for (int c = 0; c < 9; ++c) {                     // 9 z-rows, plump (~24 pts)
        const int X = X0 + c / 3, Y = Y0 + c % 3;
        const int rb = (X << 6) | (Y << 3);
        const int pe = cs[rb + Z0 + SW];
        for (int p = cs[rb + Z0] + r; p < pe; p += 8) {
            const float4 cd = pts[p];
            const float ddx = cd.x - me.x;
            const float ddy = cd.y - me.y;
            const float ddz = cd.z - me.z;
            const float d = fmaf(ddz, ddz, fmaf(ddy, ddy, ddx * ddx));
            INS6(L, d);
        }
    }

    // Exact union-top-6 across the 8 disjoint sublane slices (butterfly).
    #pragma unroll
    for (int m = 1; m <= 4; m <<= 1) {
        float R[6];
        #pragma unroll
        for (int i = 0; i < 6; ++i) R[i] = __shfl_xor(L[i], m, 64);
        #pragma unroll
        for (int i = 0; i < 6; ++i) INS6(L, R[i]);
    }

    // Per-query coverage radius: distance to nearest non-boundary window face.
    float cov = 1e30f;
    if (X0 != 0)          cov = fminf(cov, me.x - (float)X0 * HCELL);
    if (X0 != GRIDD - SW) cov = fminf(cov, (float)(X0 + SW) * HCELL - me.x);
    if (Y0 != 0)          cov = fminf(cov, me.y - (float)Y0 * HCELL);
    if (Y0 != GRIDD - SW) cov = fminf(cov, (float)(Y0 + SW) * HCELL - me.y);
    if (Z0 != 0)          cov = fminf(cov, me.z - (float)Z0 * HCELL);
    if (Z0 != GRIDD - SW) cov = fminf(cov, (float)(Z0 + SW) * HCELL - me.z);

    const bool owner = (r == 0);
    const bool ok    = (L[5] <= cov * cov);
    float loss = (owner && ok) ? loss5(L) : 0.0f;

    // Exact full-batch scan from LDS for flagged queries (essentially never).
    unsigned long long flagged = __ballot(owner && !ok);
    while (flagged) {
        const int src = __ffsll(flagged) - 1;
        flagged &= flagged - 1;
        const float mx = __shfl(me.x, src, 64);
        const float my = __shfl(me.y, src, 64);
        const float mz = __shfl(me.z, src, 64);
        float F[6];
        #pragma unroll
        for (int i = 0; i < 6; ++i) F[i] = 1e30f;
        for (int p2 = lane; p2 < NPTS; p2 += 64) {
            const float4 cd = pts[p2];
            const float ddx = cd.x - mx;
            const float ddy = cd.y - my;
            const float ddz = cd.z - mz;
            const float d = fmaf(ddz, ddz, fmaf(ddy, ddy, ddx * ddx));
            INS6(F, d);
        }
        #pragma unroll
        for (int off = 32; off >= 1; off >>= 1) {     // tree merge -> lane 0
            float R[6];
            #pragma unroll
            for (int i = 0; i < 6; ++i) R[i] = __shfl_down(F[i], off, 64);
            #pragma unroll
            for (int i = 0; i < 6; ++i) INS6(F, R[i]);
        }
        if (lane == 0) loss += loss5(F);
    }

    #pragma unroll
    for (int off = 32; off > 0; off >>= 1)
        loss += __shfl_down(loss, off, 64);
    const int wave = t >> 6;
    if (lane == 0) red[wave] = loss;
    __syncthreads();
    if (t == 0) {
        float ssum = 0.0f;
        #pragma unroll
        for (int w = 0; w < 16; ++w) ssum += red[w];
        partial[blockIdx.x] = ssum;   // block = 128 consecutive queries
    }
}

// 512 partials (32 per batch): thread t -> batch t>>4, 2 partials, 16-lane reduce.
__global__ void final_kernel(const float* __restrict__ partial,
                             float* __restrict__ out)
{
    const int t = threadIdx.x;
    const int bb = t >> 4, j = t & 15;
    float s = partial[bb * 32 + j] + partial[bb * 32 + 16 + j];
    #pragma unroll
    for (int off = 8; off > 0; off >>= 1)
        s += __shfl_down(s, off, 16);
    if (j == 0) out[bb] = s * (1.0f / ((float)NPTS * 5.0f));
}

// ---------------------------------------------------------------------------
// Emergency path (tiny workspace): monolithic brute force.
// ---------------------------------------------------------------------------
__global__ __launch_bounds__(256) void mono_kernel(
    const float* __restrict__ pred, float* __restrict__ partial)
{
    __shared__ __align__(16) float sx[NPTS];
    __shared__ __align__(16) float sy[NPTS];
    __shared__ __align__(16) float sz[NPTS];
    __shared__ float red[4];

    const int b     = blockIdx.x >> 4;
    const int chunk = blockIdx.x & 15;
    const float* pb = pred + (size_t)b * NPTS * 3;

    for (int p = threadIdx.x; p < NPTS; p += 256) {
        sx[p] = pb[3 * p + 0]; sy[p] = pb[3 * p + 1]; sz[p] = pb[3 * p + 2];
    }
    __syncthreads();

    const int n = chunk * 256 + threadIdx.x;
    const float qx = pb[3 * n], qy = pb[3 * n + 1], qz = pb[3 * n + 2];

    float A[6], B[6];
    #pragma unroll
    for (int i = 0; i < 6; ++i) { A[i] = 1e30f; B[i] = 1e30f; }

    const float4* X4 = (const float4*)sx;
    const float4* Y4 = (const float4*)sy;
    const float4* Z4 = (const float4*)sz;

    #pragma unroll 2
    for (int g = 0; g < NPTS / 4; ++g) {
        const float4 X = X4[g], Y = Y4[g], Z = Z4[g];
        const float dx0 = X.x - qx, dy0 = Y.x - qy, dz0 = Z.x - qz;
        const float dx1 = X.y - qx, dy1 = Y.y - qy, dz1 = Z.y - qz;
        const float dx2 = X.z - qx, dy2 = Y.z - qy, dz2 = Z.z - qz;
        const float dx3 = X.w - qx, dy3 = Y.w - qy, dz3 = Z.w - qz;
        const float d0 = fmaf(dz0, dz0, fmaf(dy0, dy0, dx0 * dx0));
        const float d1 = fmaf(dz1, dz1, fmaf(dy1, dy1, dx1 * dx1));
        const float d2 = fmaf(dz2, dz2, fmaf(dy2, dy2, dx2 * dx2));
        const float d3 = fmaf(dz3, dz3, fmaf(dy3, dy3, dx3 * dx3));
        INS6(A, d0);
        INS6(B, d1);
        INS6(A, d2);
        INS6(B, d3);
    }
    #pragma unroll
    for (int i = 0; i < 6; ++i) INS6(A, B[i]);

    float loss = loss5(A);
    #pragma unroll
    for (int off = 32; off > 0; off >>= 1)
        loss += __shfl_down(loss, off, 64);
    const int wave = threadIdx.x >> 6, lane = threadIdx.x & 63;
    if (lane == 0) red[wave] = loss;
    __syncthreads();
    if (threadIdx.x == 0) {
        float s = 0.0f;
        #pragma unroll
        for (int w = 0; w < 4; ++w) s += red[w];
        partial[blockIdx.x] = s;
    }
}

__global__ void mono_final_kernel(const float* __restrict__ partial,
                                  float* __restrict__ out)
{
    const int b = threadIdx.x;
    if (b < NB) {
        float s = 0.0f;
        #pragma unroll
        for (int i = 0; i < 16; ++i) s += partial[b * 16 + i];
        out[b] = s * (1.0f / ((float)NPTS * 5.0f));
    }
}

extern "C" void kernel_launch(void* const* d_in, const int* in_sizes, int n_in,
                              void* d_out, int out_size, void* d_ws, size_t ws_size,
                              hipStream_t stream)
{
    const float* pred = (const float*)d_in[0];
    float* out        = (float*)d_out;
    char* ws          = (char*)d_ws;

    const size_t off_sorted = 0;                               // 1 MB
    const size_t off_cs     = off_sorted + (size_t)NB * NPTS * sizeof(float4);
    const size_t off_part   = off_cs + (size_t)NB * (NCELL + 1) * sizeof(int);
    const size_t need       = off_part + 512 * sizeof(float);

    if (ws_size >= need) {
        float4* sortedP = (float4*)(ws + off_sorted);
        int*    cellS   = (int*)(ws + off_cs);
        float*  partial = (float*)(ws + off_part);

        bin_kernel<<<dim3(NB), dim3(512), 0, stream>>>(pred, sortedP, cellS);
        search_kernel<<<dim3(NB * 32), dim3(1024), 0, stream>>>(
            sortedP, cellS, partial);
        final_kernel<<<dim3(1), dim3(256), 0, stream>>>(partial, out);
    } else {
        float* partial = (float*)d_ws;                 // 256 floats
        mono_kernel<<<dim3(256), dim3(256), 0, stream>>>(pred, partial);
        mono_final_kernel<<<dim3(1), dim3(64), 0, stream>>>(partial, out);
    }
}

// Round 9
// 30.499 us; speedup vs baseline: 1.2879x; 1.1191x over previous
//
#include <hip/hip_runtime.h>
#include <math.h>

#define NPTS 4096
#define NB 16
#define RADIUSF 0.07f
#define HF 0.03f
#define EPSF 1e-12f

#define GRIDD 8
#define NCELL (GRIDD * GRIDD * GRIDD)   // 512
#define HCELL 0.125f                    // cell edge
#define SW 3                            // search window (cells per axis)

// Insert d into sorted-ascending 6-list: L0'=min(L0,d), Lk'=med3(d,L(k-1),Lk).
#define INS6(L, dd) do {                                          \
    const float _d  = (dd);                                       \
    const float _n0 = fminf((L)[0], _d);                          \
    const float _n1 = __builtin_amdgcn_fmed3f(_d, (L)[0], (L)[1]);\
    const float _n2 = __builtin_amdgcn_fmed3f(_d, (L)[1], (L)[2]);\
    const float _n3 = __builtin_amdgcn_fmed3f(_d, (L)[2], (L)[3]);\
    const float _n4 = __builtin_amdgcn_fmed3f(_d, (L)[3], (L)[4]);\
    const float _n5 = __builtin_amdgcn_fmed3f(_d, (L)[4], (L)[5]);\
    (L)[0]=_n0; (L)[1]=_n1; (L)[2]=_n2; (L)[3]=_n3; (L)[4]=_n4; (L)[5]=_n5; \
} while (0)

__device__ __forceinline__ float loss5(const float* L) {
    float loss = 0.0f;
    #pragma unroll
    for (int i = 1; i < 6; ++i) {               // L[0] == self (exact 0)
        const float d = sqrtf(fmaxf(L[i], EPSF));
        const float t = d / HF;
        loss += (RADIUSF - d) * expf(-t * t);
    }
    return loss;
}

// ---------------------------------------------------------------------------
// Fused kernel: each block (1024 thr, 16 waves) counting-sorts its batch into
// SoA LDS (x|y|z planes), then grid-searches 128 queries (by ORIGINAL index;
// per-block scatter permutations differ, but top-6 VALUES of a multiset via
// min/med3 are insertion-order-invariant -> bit-deterministic output).
// 8 sublanes/query stride the 9 z-rows of the shifted-clamped 3^3 window;
// butterfly exact merge; per-query coverage proof; rare failures scanned
// exactly from LDS. SoA b32 reads: sublane runs hit consecutive banks
// (~2-way aliasing = free) instead of the 8-way float4 gather conflicts.
// ---------------------------------------------------------------------------
__global__ __launch_bounds__(1024, 8) void fused_search_kernel(
    const float* __restrict__ pred, float* __restrict__ partial)
{
    __shared__ float spts[3 * NPTS];     // x | y | z planes, 48 KB
    __shared__ int h[NCELL];             // 2 KB
    __shared__ int cur[NCELL];           // 2 KB
    __shared__ int cstart[NCELL + 1];    // 2 KB
    __shared__ int wsum[8], wpre[8];
    __shared__ float red[16];

    const int b     = blockIdx.x >> 5;                // batch
    const int chunk = blockIdx.x & 31;                // 128-query chunk
    const int t = threadIdx.x, lane = t & 63, w = t >> 6;

    if (t < NCELL) { h[t] = 0; cur[t] = 0; }
    __syncthreads();

    // ---- Bin: 4 points/thread via 3 coalesced float4 loads.
    const float4* pb4 = (const float4*)(pred + (size_t)b * NPTS * 3);
    const float4 A = pb4[3 * t], B = pb4[3 * t + 1], C = pb4[3 * t + 2];
    const float px[4] = { A.x, A.w, B.z, C.y };
    const float py[4] = { A.y, B.x, B.w, C.z };
    const float pz[4] = { A.z, B.y, C.x, C.w };

    int cid[4];
    #pragma unroll
    for (int k = 0; k < 4; ++k) {
        const int ix = min(GRIDD - 1, max(0, (int)(px[k] * (float)GRIDD)));
        const int iy = min(GRIDD - 1, max(0, (int)(py[k] * (float)GRIDD)));
        const int iz = min(GRIDD - 1, max(0, (int)(pz[k] * (float)GRIDD)));
        cid[k] = (ix << 6) | (iy << 3) | iz;
        atomicAdd(&h[cid[k]], 1);
    }
    __syncthreads();

    // Scan (512 active threads = waves 0..7): wave shfl scan + 8-wave prefix.
    int vv = 0, hv = 0;
    if (t < NCELL) {
        hv = h[t]; vv = hv;
        #pragma unroll
        for (int off = 1; off < 64; off <<= 1) {
            const int u = __shfl_up(vv, off, 64);
            if (lane >= off) vv += u;
        }
        if (lane == 63) wsum[w] = vv;
    }
    __syncthreads();
    if (t < 8) {
        int s = 0;
        for (int i = 0; i < t; ++i) s += wsum[i];
        wpre[t] = s;
    }
    __syncthreads();
    if (t < NCELL) cstart[t] = vv + wpre[w] - hv;     // exclusive start
    if (t == NCELL) cstart[NCELL] = NPTS;
    __syncthreads();

    #pragma unroll
    for (int k = 0; k < 4; ++k) {
        const int dst = cstart[cid[k]] + atomicAdd(&cur[cid[k]], 1);
        spts[dst]            = px[k];
        spts[NPTS + dst]     = py[k];
        spts[2 * NPTS + dst] = pz[k];
    }
    __syncthreads();

    // ---- Search: query = ORIGINAL point id (partition independent of scatter).
    const int qn = chunk * 128 + (t >> 3);
    const int r  = t & 7;                             // sublane 0..7
    const float* pq = pred + (size_t)b * NPTS * 3 + 3 * qn;
    const float mex = pq[0], mey = pq[1], mez = pq[2];

    const int ix = min(GRIDD - 1, max(0, (int)(mex * (float)GRIDD)));
    const int iy = min(GRIDD - 1, max(0, (int)(mey * (float)GRIDD)));
    const int iz = min(GRIDD - 1, max(0, (int)(mez * (float)GRIDD)));
    const int X0 = min(max(ix - 1, 0), GRIDD - SW);   // shifted-clamped window
    const int Y0 = min(max(iy - 1, 0), GRIDD - SW);
    const int Z0 = min(max(iz - 1, 0), GRIDD - SW);

    float L[6];
    #pragma unroll
    for (int i = 0; i < 6; ++i) L[i] = 1e30f;

    #pragma unroll
    for (int c = 0; c < 9; ++c) {                     // 9 plump z-rows (~24 pts)
        const int X = X0 + c / 3, Y = Y0 + c % 3;
        const int rb = (X << 6) | (Y << 3);
        const int pe = cstart[rb + Z0 + SW];
        for (int p = cstart[rb + Z0] + r; p < pe; p += 8) {
            const float ddx = spts[p] - mex;
            const float ddy = spts[NPTS + p] - mey;
            const float ddz = spts[2 * NPTS + p] - mez;
            const float d = fmaf(ddz, ddz, fmaf(ddy, ddy, ddx * ddx));
            INS6(L, d);
        }
    }

    // Exact union-top-6 across the 8 disjoint sublane slices (butterfly).
    #pragma unroll
    for (int m = 1; m <= 4; m <<= 1) {
        float R[6];
        #pragma unroll
        for (int i = 0; i < 6; ++i) R[i] = __shfl_xor(L[i], m, 64);
        #pragma unroll
        for (int i = 0; i < 6; ++i) INS6(L, R[i]);
    }

    // Per-query coverage radius: distance to nearest non-boundary window face.
    float cov = 1e30f;
    if (X0 != 0)          cov = fminf(cov, mex - (float)X0 * HCELL);
    if (X0 != GRIDD - SW) cov = fminf(cov, (float)(X0 + SW) * HCELL - mex);
    if (Y0 != 0)          cov = fminf(cov, mey - (float)Y0 * HCELL);
    if (Y0 != GRIDD - SW) cov = fminf(cov, (float)(Y0 + SW) * HCELL - mey);
    if (Z0 != 0)          cov = fminf(cov, mez - (float)Z0 * HCELL);
    if (Z0 != GRIDD - SW) cov = fminf(cov, (float)(Z0 + SW) * HCELL - mez);

    const bool owner = (r == 0);
    const bool ok    = (L[5] <= cov * cov);
    float loss = (owner && ok) ? loss5(L) : 0.0f;

    // Exact full-batch scan from LDS for flagged queries (essentially never).
    unsigned long long flagged = __ballot(owner && !ok);
    while (flagged) {
        const int src = __ffsll(flagged) - 1;
        flagged &= flagged - 1;
        const float fx = __shfl(mex, src, 64);
        const float fy = __shfl(mey, src, 64);
        const float fz = __shfl(mez, src, 64);
        float F[6];
        #pragma unroll
        for (int i = 0; i < 6; ++i) F[i] = 1e30f;
        for (int p2 = lane; p2 < NPTS; p2 += 64) {
            const float ddx = spts[p2] - fx;
            const float ddy = spts[NPTS + p2] - fy;
            const float ddz = spts[2 * NPTS + p2] - fz;
            const float d = fmaf(ddz, ddz, fmaf(ddy, ddy, ddx * ddx));
            INS6(F, d);
        }
        #pragma unroll
        for (int off = 32; off >= 1; off >>= 1) {     // tree merge -> lane 0
            float R[6];
            #pragma unroll
            for (int i = 0; i < 6; ++i) R[i] = __shfl_down(F[i], off, 64);
            #pragma unroll
            for (int i = 0; i < 6; ++i) INS6(F, R[i]);
        }
        if (lane == 0) loss += loss5(F);
    }

    #pragma unroll
    for (int off = 32; off > 0; off >>= 1)
        loss += __shfl_down(loss, off, 64);
    if (lane == 0) red[w] = loss;
    __syncthreads();
    if (t == 0) {
        float ssum = 0.0f;
        #pragma unroll
        for (int i = 0; i < 16; ++i) ssum += red[i];
        partial[blockIdx.x] = ssum;   // block = 128 consecutive queries
    }
}

// 512 partials (32 per batch): thread t -> batch t>>4, 2 partials, 16-lane reduce.
__global__ void final_kernel(const float* __restrict__ partial,
                             float* __restrict__ out)
{
    const int t = threadIdx.x;
    const int bb = t >> 4, j = t & 15;
    float s = partial[bb * 32 + j] + partial[bb * 32 + 16 + j];
    #pragma unroll
    for (int off = 8; off > 0; off >>= 1)
        s += __shfl_down(s, off, 16);
    if (j == 0) out[bb] = s * (1.0f / ((float)NPTS * 5.0f));
}

// ---------------------------------------------------------------------------
// Emergency path (tiny workspace): monolithic brute force.
// ---------------------------------------------------------------------------
__global__ __launch_bounds__(256) void mono_kernel(
    const float* __restrict__ pred, float* __restrict__ partial)
{
    __shared__ __align__(16) float sx[NPTS];
    __shared__ __align__(16) float sy[NPTS];
    __shared__ __align__(16) float sz[NPTS];
    __shared__ float red[4];

    const int b     = blockIdx.x >> 4;
    const int chunk = blockIdx.x & 15;
    const float* pb = pred + (size_t)b * NPTS * 3;

    for (int p = threadIdx.x; p < NPTS; p += 256) {
        sx[p] = pb[3 * p + 0]; sy[p] = pb[3 * p + 1]; sz[p] = pb[3 * p + 2];
    }
    __syncthreads();

    const int n = chunk * 256 + threadIdx.x;
    const float qx = pb[3 * n], qy = pb[3 * n + 1], qz = pb[3 * n + 2];

    float A[6], B[6];
    #pragma unroll
    for (int i = 0; i < 6; ++i) { A[i] = 1e30f; B[i] = 1e30f; }

    const float4* X4 = (const float4*)sx;
    const float4* Y4 = (const float4*)sy;
    const float4* Z4 = (const float4*)sz;

    #pragma unroll 2
    for (int g = 0; g < NPTS / 4; ++g) {
        const float4 X = X4[g], Y = Y4[g], Z = Z4[g];
        const float dx0 = X.x - qx, dy0 = Y.x - qy, dz0 = Z.x - qz;
        const float dx1 = X.y - qx, dy1 = Y.y - qy, dz1 = Z.y - qz;
        const float dx2 = X.z - qx, dy2 = Y.z - qy, dz2 = Z.z - qz;
        const float dx3 = X.w - qx, dy3 = Y.w - qy, dz3 = Z.w - qz;
        const float d0 = fmaf(dz0, dz0, fmaf(dy0, dy0, dx0 * dx0));
        const float d1 = fmaf(dz1, dz1, fmaf(dy1, dy1, dx1 * dx1));
        const float d2 = fmaf(dz2, dz2, fmaf(dy2, dy2, dx2 * dx2));
        const float d3 = fmaf(dz3, dz3, fmaf(dy3, dy3, dx3 * dx3));
        INS6(A, d0);
        INS6(B, d1);
        INS6(A, d2);
        INS6(B, d3);
    }
    #pragma unroll
    for (int i = 0; i < 6; ++i) INS6(A, B[i]);

    float loss = loss5(A);
    #pragma unroll
    for (int off = 32; off > 0; off >>= 1)
        loss += __shfl_down(loss, off, 64);
    const int wave = threadIdx.x >> 6, lane = threadIdx.x & 63;
    if (lane == 0) red[wave] = loss;
    __syncthreads();
    if (threadIdx.x == 0) {
        float s = 0.0f;
        #pragma unroll
        for (int w = 0; w < 4; ++w) s += red[w];
        partial[blockIdx.x] = s;
    }
}

__global__ void mono_final_kernel(const float* __restrict__ partial,
                                  float* __restrict__ out)
{
    const int b = threadIdx.x;
    if (b < NB) {
        float s = 0.0f;
        #pragma unroll
        for (int i = 0; i < 16; ++i) s += partial[b * 16 + i];
        out[b] = s * (1.0f / ((float)NPTS * 5.0f));
    }
}

extern "C" void kernel_launch(void* const* d_in, const int* in_sizes, int n_in,
                              void* d_out, int out_size, void* d_ws, size_t ws_size,
                              hipStream_t stream)
{
    const float* pred = (const float*)d_in[0];
    float* out        = (float*)d_out;
    float* partial    = (float*)d_ws;

    if (ws_size >= 512 * sizeof(float)) {
        fused_search_kernel<<<dim3(NB * 32), dim3(1024), 0, stream>>>(pred, partial);
        final_kernel<<<dim3(1), dim3(256), 0, stream>>>(partial, out);
    } else {
        mono_kernel<<<dim3(256), dim3(256), 0, stream>>>(pred, partial);
        mono_final_kernel<<<dim3(1), dim3(64), 0, stream>>>(partial, out);
    }
}